// Round 3
// baseline (219.710 us; speedup 1.0000x reference)
//
#include <hip/hip_runtime.h>

// Problem constants (from reference)
#define ZD_ 64
#define PD_ 16
#define DH_ 128

// ---------------------------------------------------------------------------
// K0: hid[64][128] = relu([z_all | pde] @ W1^T + b1)   (unchanged, ~2 µs)
// ---------------------------------------------------------------------------
__global__ void hid_kernel(const float* __restrict__ z_all,
                           const float* __restrict__ W1,
                           const float* __restrict__ b1,
                           const float* __restrict__ pde,
                           float* __restrict__ hid) {
    int gid = blockIdx.x * 256 + threadIdx.x;   // 8192 outputs
    int r = gid >> 7;                            // z row (0..63)
    int d = gid & 127;                           // hidden unit
    const float* w = W1 + d * (ZD_ + PD_);
    const float* z = z_all + r * ZD_;
    float acc = b1[d];
    #pragma unroll 8
    for (int c = 0; c < ZD_; ++c) acc += z[c] * w[c];
    #pragma unroll
    for (int c = 0; c < PD_; ++c) acc += pde[c] * w[ZD_ + c];
    hid[gid] = fmaxf(acc, 0.0f);
}

// ---------------------------------------------------------------------------
// K1 (fused, scalar-pipe GEMM): block = (ob, ibp) — ob 0..63, ibp = group of
// 8 consecutive ib. Grid 512 x 256 threads (4 waves).
//
// Key structural fact: 64 hypernet cells (hk = h*8+kb) == one wave.
//   lane <-> cell; hid[cell][0..127] lives in 32 float4 REGISTERS (loaded
//   once). n = ob*576 + ib*9 + k is wave-uniform -> W2 row + b2 fetched via
//   the SCALAR pipe (s_load, zero VALU/LDS cost) and each v_fmac computes
//   all 64 cells at once. Dot phase has NO LDS traffic (was 288 ds_read_b128
//   per wave = the R1 bottleneck).
//   Wave w handles ib_local = w and w+4 (9 k-rows each, 4-way split acc).
//
// exe results go to s_exe[cell][ibl*9+k] (stride 73: 9*lane mod 32 covers all
// banks -> conflict-free b32 writes). unet staged to s_un[cell][ibl*9+l]
// (stride 72: 16B-aligned float4 writes). Epilogue = identical coalesced
// float4 store pattern as R1, but now runs of 8 ib = 648 floats per cell.
// LDS 37.1 KB -> ~2 blocks/CU for the write-bound tail.
// ---------------------------------------------------------------------------
#define EXE_STRIDE 73
#define UN_STRIDE  72

__global__ __launch_bounds__(256) void fused_kernel(
        const float* __restrict__ hid,
        const float* __restrict__ W2,
        const float* __restrict__ b2,
        const float* __restrict__ unet,
        float* __restrict__ out) {
    __shared__ float s_exe[64 * EXE_STRIDE];                 // 18,688 B
    __shared__ __align__(16) float s_un[64 * UN_STRIDE];     // 18,432 B

    int tid  = threadIdx.x;
    int b    = blockIdx.x;
    int ob   = b >> 3;           // 0..63
    int ibp  = b & 7;            // 0..7  (ib0 = ibp*8)
    int wave = __builtin_amdgcn_readfirstlane(tid >> 6);
    int lane = tid & 63;         // = cell = h*8 + kb

    // --- hid row -> registers (lane = cell). 32 KB total, L1/L2-hot. ---
    float4 hreg[32];
    const float4* hp = reinterpret_cast<const float4*>(hid + lane * DH_);
    #pragma unroll
    for (int c = 0; c < 32; ++c) hreg[c] = hp[c];

    // --- stage unet: 64 cells x 72 contiguous floats (18 float4 each) ---
    for (int j = tid; j < 1152; j += 256) {
        int cell = j / 18;
        int q    = j - cell * 18;
        int hh = cell >> 3, kk = cell & 7;
        size_t gb = ((size_t)((hh * 64 + ob) * 512 + kk * 64 + ibp * 8)) * 9;
        float4 v = *reinterpret_cast<const float4*>(unet + gb + q * 4);
        *reinterpret_cast<float4*>(&s_un[cell * UN_STRIDE + q * 4]) = v;
    }

    // --- dot phase: pure scalar-load + v_fmac, no LDS reads ---
    #pragma unroll
    for (int t = 0; t < 2; ++t) {
        int ibl = wave + t * 4;                          // 0..7 local ib
        int n_base = __builtin_amdgcn_readfirstlane(
                         ob * 576 + (ibp * 8 + ibl) * 9);
        #pragma unroll
        for (int k = 0; k < 9; ++k) {
            const float* wrow = W2 + (size_t)(n_base + k) * DH_;  // uniform
            float a0 = 0.f, a1 = 0.f, a2 = 0.f, a3 = 0.f;
            #pragma unroll
            for (int c = 0; c < 32; c += 4) {
                float4 w0 = *reinterpret_cast<const float4*>(wrow + c * 4);
                float4 w1 = *reinterpret_cast<const float4*>(wrow + c * 4 + 4);
                float4 w2 = *reinterpret_cast<const float4*>(wrow + c * 4 + 8);
                float4 w3 = *reinterpret_cast<const float4*>(wrow + c * 4 + 12);
                a0 += w0.x * hreg[c+0].x + w0.y * hreg[c+0].y
                    + w0.z * hreg[c+0].z + w0.w * hreg[c+0].w;
                a1 += w1.x * hreg[c+1].x + w1.y * hreg[c+1].y
                    + w1.z * hreg[c+1].z + w1.w * hreg[c+1].w;
                a2 += w2.x * hreg[c+2].x + w2.y * hreg[c+2].y
                    + w2.z * hreg[c+2].z + w2.w * hreg[c+2].w;
                a3 += w3.x * hreg[c+3].x + w3.y * hreg[c+3].y
                    + w3.z * hreg[c+3].z + w3.w * hreg[c+3].w;
            }
            float acc = b2[n_base + k] + ((a0 + a1) + (a2 + a3));
            s_exe[lane * EXE_STRIDE + ibl * 9 + k] = acc;   // conflict-free
        }
    }
    __syncthreads();

    // --- epilogue: outer product, 64 runs x 162 float4 (coalesced) ---
    for (int idx = tid; idx < 10368; idx += 256) {
        int cell = idx / 162;
        int q    = idx - cell * 162;
        float4 v;
        float* vp = &v.x;
        #pragma unroll
        for (int j2 = 0; j2 < 4; ++j2) {
            int e   = q * 4 + j2;          // 0..647 within run
            int ibl = e / 81;
            int rem = e - ibl * 81;
            int k   = rem / 9;
            int l   = rem - k * 9;
            vp[j2] = s_exe[cell * EXE_STRIDE + ibl * 9 + k]
                   * s_un [cell * UN_STRIDE  + ibl * 9 + l];
        }
        int hh = cell >> 3, kk = cell & 7;
        size_t gb = ((size_t)((hh * 64 + ob) * 512 + kk * 64 + ibp * 8)) * 81;
        reinterpret_cast<float4*>(out + gb)[q] = v;   // 16B-aligned
    }
}

// ---------------------------------------------------------------------------
extern "C" void kernel_launch(void* const* d_in, const int* in_sizes, int n_in,
                              void* d_out, int out_size, void* d_ws, size_t ws_size,
                              hipStream_t stream) {
    const float* z_all = (const float*)d_in[0];  // [64,64]
    const float* W1    = (const float*)d_in[1];  // [128,80]
    const float* b1    = (const float*)d_in[2];  // [128]
    const float* W2    = (const float*)d_in[3];  // [36864,128]
    const float* b2    = (const float*)d_in[4];  // [36864]
    const float* unet  = (const float*)d_in[5];  // [512,512,9]
    const float* pde   = (const float*)d_in[6];  // [16]
    float* out = (float*)d_out;                  // [512,512,9,9]

    float* hid = (float*)d_ws;                   // 8192 floats

    hid_kernel<<<32, 256, 0, stream>>>(z_all, W1, b1, pde, hid);
    fused_kernel<<<512, 256, 0, stream>>>(hid, W2, b2, unet, out);
}

// Round 4
// 137.394 us; speedup vs baseline: 1.5991x; 1.5991x over previous
//
#include <hip/hip_runtime.h>

#define ZD_ 64
#define PD_ 16
#define DH_ 128

// ---------------------------------------------------------------------------
// K0: hidT[d][r] = relu([z_all | pde] @ W1^T + b1), TRANSPOSED output.
// gid -> d = gid>>6 (wave-uniform: W1 row via scalar loads), r = gid&63.
// Writes hidT[d*64+r]: consecutive lanes -> consecutive r -> coalesced.
// ---------------------------------------------------------------------------
__global__ void hid_kernel(const float* __restrict__ z_all,
                           const float* __restrict__ W1,
                           const float* __restrict__ b1,
                           const float* __restrict__ pde,
                           float* __restrict__ hidT) {
    int gid = blockIdx.x * 256 + threadIdx.x;   // 8192 outputs
    int d = gid >> 6;                            // hidden unit (wave-uniform)
    int r = gid & 63;                            // z row
    const float* w = W1 + d * (ZD_ + PD_);
    const float* z = z_all + r * ZD_;
    float acc = b1[d];
    #pragma unroll 8
    for (int c = 0; c < ZD_; ++c) acc += z[c] * w[c];
    #pragma unroll
    for (int c = 0; c < PD_; ++c) acc += pde[c] * w[ZD_ + c];
    hidT[d * 64 + r] = fmaxf(acc, 0.0f);
}

// ---------------------------------------------------------------------------
// K1 fused: block = (ob, ibp8), n0 = ob*576 + ibp*72 (72 W2 rows = 8 ib x 9 k).
// 256 threads: thread = (cg 0..15, ibl 0..7, ks 0..1).
//   Register tile: 4 cells (4cg..4cg+3) x 9 k-rows (ib = ibp*8+ibl), over the
//   ks-th half of K=128. Per 4-c chunk: 4 b128 (hidT, 4 cells) + 9 b128 (W2)
//   feed 144 fmacs -> 1.44 B LDS/fmac (R1 was 4 B/fmac = the 23 us dot).
// LDS phase 1: s_w2[72][132] (38.0 KB) + s_hT[128][68] (34.8 KB) = 72.8 KB
//   -> 2 blocks/CU, 8 waves/CU. All strides conflict-free (broadcast/2-way).
// LDS phase 2 (aliased after barrier): s_exe[64][73] + s_red[128][37] in the
//   s_w2 region; s_un[64][72] in the s_hT region.
// K-split combine: ks=1 waves dump acc to s_red (pad 37 -> 2-way banks);
//   ks=0 waves add partner partial + write s_exe. Branches are wave-uniform.
// Epilogue: identical coalesced float4 store pattern as R1/R3 (verified,
//   bank-conflict counter 0).
// ---------------------------------------------------------------------------
#define SMEM_FLOATS 18208   // 72,832 bytes

__global__ __launch_bounds__(256) void fused_kernel(
        const float* __restrict__ hidT,
        const float* __restrict__ W2,
        const float* __restrict__ b2,
        const float* __restrict__ unet,
        float* __restrict__ out) {
    __shared__ __align__(16) float smem[SMEM_FLOATS];
    float* s_w2 = smem;            // 72*132 = 9504 floats
    float* s_hT = smem + 9504;     // 128*68 = 8704 floats

    int tid = threadIdx.x;
    int b   = blockIdx.x;
    int ob  = b >> 3;              // 0..63
    int ibp = b & 7;               // 0..7
    int n0  = ob * 576 + ibp * 72;

    // --- stage W2: 72 contiguous rows = 2304 float4, 9 per thread ---
    const float4* g4 = reinterpret_cast<const float4*>(W2 + (size_t)n0 * DH_);
    #pragma unroll
    for (int t = 0; t < 9; ++t) {
        int j   = t * 256 + tid;
        int row = j >> 5;          // 0..71
        int c4  = j & 31;
        *reinterpret_cast<float4*>(&s_w2[row * 132 + c4 * 4]) = g4[j];
    }
    // --- stage hidT: 8192 floats = 2048 float4, 8 per thread ---
    const float4* h4g = reinterpret_cast<const float4*>(hidT);
    #pragma unroll
    for (int t = 0; t < 8; ++t) {
        int j  = t * 256 + tid;
        int d  = j >> 4;           // k index 0..127
        int r4 = j & 15;           // cell-quad
        *reinterpret_cast<float4*>(&s_hT[d * 68 + r4 * 4]) = h4g[j];
    }

    int cg  = tid & 15;            // cells 4cg..4cg+3
    int ibl = (tid >> 4) & 7;      // local ib
    int ks  = tid >> 7;            // k-half (wave-uniform)

    float4 acc[9];
    if (ks == 0) {
        #pragma unroll
        for (int kk = 0; kk < 9; ++kk) {
            float bv = b2[n0 + ibl * 9 + kk];
            acc[kk] = make_float4(bv, bv, bv, bv);
        }
    } else {
        #pragma unroll
        for (int kk = 0; kk < 9; ++kk) acc[kk] = make_float4(0.f, 0.f, 0.f, 0.f);
    }
    __syncthreads();

    // --- dot: 16 chunks of 4 c-values over this thread's K-half ---
    const float* wbase = s_w2 + ibl * 9 * 132 + ks * 64;
    const float* hbase = s_hT + (size_t)ks * 64 * 68 + 4 * cg;
    #pragma unroll 2
    for (int cc = 0; cc < 64; cc += 4) {
        float4 h0 = *reinterpret_cast<const float4*>(&hbase[(cc + 0) * 68]);
        float4 h1 = *reinterpret_cast<const float4*>(&hbase[(cc + 1) * 68]);
        float4 h2 = *reinterpret_cast<const float4*>(&hbase[(cc + 2) * 68]);
        float4 h3 = *reinterpret_cast<const float4*>(&hbase[(cc + 3) * 68]);
        #pragma unroll
        for (int kk = 0; kk < 9; ++kk) {
            float4 w = *reinterpret_cast<const float4*>(&wbase[kk * 132 + cc]);
            acc[kk].x += h0.x * w.x + h1.x * w.y + h2.x * w.z + h3.x * w.w;
            acc[kk].y += h0.y * w.x + h1.y * w.y + h2.y * w.z + h3.y * w.w;
            acc[kk].z += h0.z * w.x + h1.z * w.y + h2.z * w.z + h3.z * w.w;
            acc[kk].w += h0.w * w.x + h1.w * w.y + h2.w * w.z + h3.w * w.w;
        }
    }
    __syncthreads();   // all s_w2 / s_hT reads complete -> safe to alias

    float* s_exe = smem;           // 64*73 = 4672 floats
    float* s_red = smem + 4672;    // 128*37 = 4736 floats (ends 9408 < 9504)
    float* s_un  = smem + 9504;    // 64*72 = 4608 floats

    if (ks == 1) {                 // waves 2,3: dump partials
        int slot = tid & 127;
        #pragma unroll
        for (int kk = 0; kk < 9; ++kk) {
            s_red[slot * 37 + 0 * 9 + kk] = acc[kk].x;
            s_red[slot * 37 + 1 * 9 + kk] = acc[kk].y;
            s_red[slot * 37 + 2 * 9 + kk] = acc[kk].z;
            s_red[slot * 37 + 3 * 9 + kk] = acc[kk].w;
        }
    }
    // stage unet (all threads): 64 cells x 18 float4
    for (int j = tid; j < 1152; j += 256) {
        int cell = j / 18;
        int q    = j - cell * 18;
        int hh = cell >> 3, kb = cell & 7;
        size_t gb = ((size_t)((hh * 64 + ob) * 512 + kb * 64 + ibp * 8)) * 9;
        *reinterpret_cast<float4*>(&s_un[cell * 72 + q * 4]) =
            *reinterpret_cast<const float4*>(unet + gb + q * 4);
    }
    __syncthreads();

    if (ks == 0) {                 // waves 0,1: combine + write s_exe
        #pragma unroll
        for (int kk = 0; kk < 9; ++kk) {
            int col = ibl * 9 + kk;
            s_exe[(4 * cg + 0) * 73 + col] = acc[kk].x + s_red[tid * 37 + 0 * 9 + kk];
            s_exe[(4 * cg + 1) * 73 + col] = acc[kk].y + s_red[tid * 37 + 1 * 9 + kk];
            s_exe[(4 * cg + 2) * 73 + col] = acc[kk].z + s_red[tid * 37 + 2 * 9 + kk];
            s_exe[(4 * cg + 3) * 73 + col] = acc[kk].w + s_red[tid * 37 + 3 * 9 + kk];
        }
    }
    __syncthreads();

    // --- epilogue: 64 runs x 162 float4, coalesced stores ---
    for (int idx = tid; idx < 10368; idx += 256) {
        int cell = idx / 162;
        int q    = idx - cell * 162;
        float4 v;
        float* vp = &v.x;
        #pragma unroll
        for (int j2 = 0; j2 < 4; ++j2) {
            int e    = q * 4 + j2;         // 0..647 within run
            int ibl2 = e / 81;
            int rem  = e - ibl2 * 81;
            int k    = rem / 9;
            int l    = rem - k * 9;
            vp[j2] = s_exe[cell * 73 + ibl2 * 9 + k]
                   * s_un [cell * 72 + ibl2 * 9 + l];
        }
        int hh = cell >> 3, kb = cell & 7;
        size_t gb = ((size_t)((hh * 64 + ob) * 512 + kb * 64 + ibp * 8)) * 81;
        reinterpret_cast<float4*>(out + gb)[q] = v;   // 16B-aligned
    }
}

// ---------------------------------------------------------------------------
extern "C" void kernel_launch(void* const* d_in, const int* in_sizes, int n_in,
                              void* d_out, int out_size, void* d_ws, size_t ws_size,
                              hipStream_t stream) {
    const float* z_all = (const float*)d_in[0];  // [64,64]
    const float* W1    = (const float*)d_in[1];  // [128,80]
    const float* b1    = (const float*)d_in[2];  // [128]
    const float* W2    = (const float*)d_in[3];  // [36864,128]
    const float* b2    = (const float*)d_in[4];  // [36864]
    const float* unet  = (const float*)d_in[5];  // [512,512,9]
    const float* pde   = (const float*)d_in[6];  // [16]
    float* out = (float*)d_out;                  // [512,512,9,9]

    float* hidT = (float*)d_ws;                  // 8192 floats, [128][64]

    hid_kernel<<<32, 256, 0, stream>>>(z_all, W1, b1, pde, hidT);
    fused_kernel<<<512, 256, 0, stream>>>(hidT, W2, b2, unet, out);
}